// Round 4
// baseline (113.564 us; speedup 1.0000x reference)
//
#include <hip/hip_runtime.h>

#define N_IN   4096
#define N_OUT  4082      // 4096 - 15 + 1
#define KS     15
#define TM     128       // output rows per block
#define TN     256       // output cols per block
#define NCH    4         // column chunks per block
#define CW     64        // output cols per chunk
#define PR     142       // patch rows staged (TM + KS - 1)
#define PC     80        // bf16 cols per chunk row (CW + 16 halo)
#define C4     20        // float4 chunks per patch row (PC/4)
#define NITEMS (PR * C4)           // 2840 staging items per chunk
#define LDSE   (PR * PC)           // ushorts per buffer = 11360 (22720 B)

// Bank note: pitch 80 bf16 = 160 B = 40 words -> row-to-row quad shift = 2.
// ds_read_b128: group g (16 lanes, 16 consecutive rows) -> quads (10r+2t+g)%8:
// groups {0,2} cover even quads, {1,3} odd -> 8 lanes/quad everywhere = the
// wave64 b128 floor. Linear addressing is conflict-free; NO swizzle (R3's
// 3-bit XOR into a non-power-of-two row was out-of-bounds -> corruption).

typedef __attribute__((ext_vector_type(8))) short bf16x8;
typedef __attribute__((ext_vector_type(4))) float f32x4;

__device__ inline unsigned short f2bf(float f) {   // round-to-nearest-even
    unsigned u = __builtin_bit_cast(unsigned, f);
    u += 0x7FFFu + ((u >> 16) & 1u);
    return (unsigned short)(u >> 16);
}

__global__ __launch_bounds__(512, 4) void Conv2DScratch_82025285419642_kernel(
    const float* __restrict__ x, const float* __restrict__ w,
    const float* __restrict__ bias, float* __restrict__ out)
{
    __shared__ unsigned short xs[2 * LDSE];   // 45,440 B

    const int tid  = threadIdx.x;
    const int lane = tid & 63;
    const int wv   = tid >> 6;            // 0..7 : wave owns one 16-row band
    const int m    = lane & 15;           // A row within band / D col
    const int g    = lane >> 4;           // k-group / D row group

    // bijective XCD-chunked block swizzle (512 blocks, 8 XCDs, 64 each)
    const int bid = blockIdx.x;
    const int s   = ((bid & 7) << 6) | (bid >> 3);
    const int c0  = (s & 15) * TN;        // output col base
    const int r0  = (s >> 4) * TM;        // output row base

    // ---- issue global loads for chunk cc into registers (no wait) ----
    auto issue = [&](int cc, float4 (&v)[6]) {
        const int gcb = c0 + cc * CW;
        #pragma unroll
        for (int i = 0; i < 6; ++i) {
            const int item = tid + i * 512;
            float4 t = make_float4(0.f, 0.f, 0.f, 0.f);
            if (item < NITEMS) {
                const int row = item / C4;
                const int cc4 = item - row * C4;
                const int gr  = r0 + row;
                const int gc  = gcb + cc4 * 4;
                if (gr < N_IN && gc < N_IN)
                    t = *reinterpret_cast<const float4*>(&x[(long)gr * N_IN + gc]);
            }
            v[i] = t;
        }
    };
    // ---- convert + write registers into LDS buffer b ----
    auto commit = [&](int b, float4 (&v)[6]) {
        unsigned short* bs = &xs[b ? LDSE : 0];
        #pragma unroll
        for (int i = 0; i < 6; ++i) {
            const int item = tid + i * 512;
            if (item < NITEMS) {
                const int row = item / C4;
                const int cc4 = item - row * C4;
                ushort4 bb;
                bb.x = f2bf(v[i].x); bb.y = f2bf(v[i].y);
                bb.z = f2bf(v[i].z); bb.w = f2bf(v[i].w);
                *reinterpret_cast<ushort4*>(&bs[row * PC + cc4 * 4]) = bb;
            }
        }
    };

    // ---- build the 15 constant B fragments: B[(p,q)][n] = w[p][q-n] ----
    float4 vbuf[6];
    issue(0, vbuf);                 // loads in flight while we build B frags
    bf16x8 bfrag[KS];
    #pragma unroll
    for (int p = 0; p < KS; ++p) {
        #pragma unroll
        for (int e = 0; e < 8; ++e) {
            const int q   = g * 8 + e;
            const int idx = q - m;                       // filter col
            const float vv = (idx >= 0 && idx < KS) ? w[p * KS + idx] : 0.f;
            bfrag[p][e] = (short)f2bf(vv);
        }
    }
    const float b0 = bias[0];

    commit(0, vbuf);
    __syncthreads();

    // ---- pipelined chunk loop ----
    for (int c = 0; c < NCH; ++c) {
        float4 vnext[6];
        if (c + 1 < NCH) issue(c + 1, vnext);

        // compute 4 col-tiles of chunk c from buffer c&1
        const unsigned short* bs = &xs[(c & 1) ? LDSE : 0];
        f32x4 acc[4];
        #pragma unroll
        for (int t = 0; t < 4; ++t) acc[t] = f32x4{0.f, 0.f, 0.f, 0.f};
        #pragma unroll
        for (int p = 0; p < KS; ++p) {
            const int arow = wv * 16 + m + p;            // patch row
            #pragma unroll
            for (int t = 0; t < 4; ++t) {
                const bf16x8 a = *reinterpret_cast<const bf16x8*>(
                    &bs[arow * PC + t * 16 + g * 8]);
                acc[t] = __builtin_amdgcn_mfma_f32_16x16x32_bf16(a, bfrag[p], acc[t], 0, 0, 0);
            }
        }

        if (c + 1 < NCH) {
            commit((c + 1) & 1, vnext);   // vmcnt-wait on vnext happens here
            __syncthreads();
        }

        // store chunk c outputs (overlaps next chunk's issue+compute)
        const int ocb = c0 + c * CW;
        #pragma unroll
        for (int t = 0; t < 4; ++t) {
            const int ocol = ocb + t * 16 + m;           // D col = lane&15
            if (ocol < N_OUT) {
                #pragma unroll
                for (int r = 0; r < 4; ++r) {
                    const int orow = r0 + wv * 16 + g * 4 + r;   // D row
                    if (orow < N_OUT)
                        out[(long)orow * N_OUT + ocol] = acc[t][r] + b0;
                }
            }
        }
    }
}

extern "C" void kernel_launch(void* const* d_in, const int* in_sizes, int n_in,
                              void* d_out, int out_size, void* d_ws, size_t ws_size,
                              hipStream_t stream) {
    const float* x    = (const float*)d_in[0];
    const float* w    = (const float*)d_in[1];
    const float* bias = (const float*)d_in[2];
    float* out        = (float*)d_out;

    dim3 block(512);
    dim3 grid(16 * 32);   // 512 blocks, 1D, swizzled in-kernel
    Conv2DScratch_82025285419642_kernel<<<grid, block, 0, stream>>>(x, w, bias, out);
}

// Round 5
// 63.219 us; speedup vs baseline: 1.7964x; 1.7964x over previous
//
#include <hip/hip_runtime.h>

#define N_IN   4096
#define N_OUT  4082      // 4096 - 15 + 1
#define KS     15
#define TM     128       // output rows per block
#define TN     256       // output cols per block
#define NCH    4         // column chunks per block
#define CW     64        // output cols per chunk
#define PR     142       // patch rows staged (TM + KS - 1)
#define PC     80        // bf16 cols per chunk row (CW + 16 halo)
#define C4     20        // float4 chunks per patch row (PC/4)
#define NITEMS (PR * C4)           // 2840 staging items per chunk
#define LDSE   (PR * PC)           // ushorts per buffer = 11360 (22720 B)

// Bank note: pitch 80 bf16 = 160 B = 40 words -> row-to-row quad shift = 2.
// ds_read_b128 by 16-lane groups over 16 consecutive rows spreads 8 lanes
// on every bank-quad = the wave64 b128 floor. Linear, NO swizzle (R4: 0
// measured conflicts).
// Register note: staging is split into 3-float4 halves held in NAMED vars;
// peak live ~106 regs < 128 combined VGPR+AGPR cap of __launch_bounds__(512,4).
// R4's 6-float4 arrays pushed past 128 -> scratch (WRITE_SIZE 194MB).

typedef __attribute__((ext_vector_type(8))) short bf16x8;
typedef __attribute__((ext_vector_type(4))) float f32x4;

__device__ inline unsigned short f2bf(float f) {   // round-to-nearest-even
    unsigned u = __builtin_bit_cast(unsigned, f);
    u += 0x7FFFu + ((u >> 16) & 1u);
    return (unsigned short)(u >> 16);
}
__device__ inline ushort4 f2bf4(float4 v) {
    ushort4 b; b.x = f2bf(v.x); b.y = f2bf(v.y); b.z = f2bf(v.z); b.w = f2bf(v.w);
    return b;
}

// one staging item: load (predicated) / commit
#define ISSUE_ITEM(it, gcb, v) {                                          \
    const int _row = (it) / C4;                                           \
    const int _c4  = (it) - _row * C4;                                    \
    const int _gr  = r0 + _row;                                           \
    const int _gc  = (gcb) + _c4 * 4;                                     \
    if (_gr < N_IN && _gc < N_IN)                                         \
        v = *reinterpret_cast<const float4*>(&x[_gr * N_IN + _gc]);       \
}
#define COMMIT_ITEM(it, bs, v) {                                          \
    const int _row = (it) / C4;                                           \
    const int _c4  = (it) - _row * C4;                                    \
    *reinterpret_cast<ushort4*>(&(bs)[_row * PC + _c4 * 4]) = f2bf4(v);   \
}

__global__ __launch_bounds__(512, 4) void Conv2DScratch_82025285419642_kernel(
    const float* __restrict__ x, const float* __restrict__ w,
    const float* __restrict__ bias, float* __restrict__ out)
{
    __shared__ unsigned short xs[2 * LDSE];   // 45,440 B

    const int tid  = threadIdx.x;
    const int lane = tid & 63;
    const int wv   = tid >> 6;            // 0..7 : wave owns one 16-row band
    const int m    = lane & 15;           // A row within band / D col
    const int g    = lane >> 4;           // k-group / D row group

    // bijective XCD-chunked block swizzle (512 blocks, 8 XCDs, 64 each)
    const int bid = blockIdx.x;
    const int s   = ((bid & 7) << 6) | (bid >> 3);
    const int c0  = (s & 15) * TN;        // output col base
    const int r0  = (s >> 4) * TM;        // output row base

    // ---- prologue: issue chunk 0 (both halves), build B frags, commit ----
    float4 pa0 = make_float4(0.f,0.f,0.f,0.f), pa1 = pa0, pa2 = pa0;
    float4 pb0 = pa0, pb1 = pa0, pb2 = pa0;
    ISSUE_ITEM(tid,          c0, pa0);
    ISSUE_ITEM(tid + 512,    c0, pa1);
    ISSUE_ITEM(tid + 1024,   c0, pa2);
    ISSUE_ITEM(tid + 1536,   c0, pb0);
    ISSUE_ITEM(tid + 2048,   c0, pb1);
    if (tid + 2560 < NITEMS) ISSUE_ITEM(tid + 2560, c0, pb2);

    // B[(p,q)][n] = w[p][q-n]; lane: n = m, q = g*8+e
    bf16x8 bfrag[KS];
    #pragma unroll
    for (int p = 0; p < KS; ++p) {
        #pragma unroll
        for (int e = 0; e < 8; ++e) {
            const int idx = g * 8 + e - m;               // filter col
            const float vv = (idx >= 0 && idx < KS) ? w[p * KS + idx] : 0.f;
            bfrag[p][e] = (short)f2bf(vv);
        }
    }
    const float b0 = bias[0];

    COMMIT_ITEM(tid,        xs, pa0);
    COMMIT_ITEM(tid + 512,  xs, pa1);
    COMMIT_ITEM(tid + 1024, xs, pa2);
    COMMIT_ITEM(tid + 1536, xs, pb0);
    COMMIT_ITEM(tid + 2048, xs, pb1);
    if (tid + 2560 < NITEMS) COMMIT_ITEM(tid + 2560, xs, pb2);
    __syncthreads();

    const int abase = (wv * 16 + m) * PC + g * 8;

    // ---- pipelined chunk loop ----
    for (int c = 0; c < NCH; ++c) {
        const int nbuf = (c + 1) & 1;
        unsigned short* nbs = &xs[nbuf ? LDSE : 0];
        const unsigned short* bs = &xs[(c & 1) ? LDSE : 0];
        const int gcb = c0 + (c + 1) * CW;

        float4 s0 = make_float4(0.f,0.f,0.f,0.f), s1 = s0, s2 = s0;
        if (c + 1 < NCH) {                 // issue half A of next chunk
            ISSUE_ITEM(tid,        gcb, s0);
            ISSUE_ITEM(tid + 512,  gcb, s1);
            ISSUE_ITEM(tid + 1024, gcb, s2);
        }

        f32x4 acc0 = {0.f,0.f,0.f,0.f}, acc1 = acc0, acc2 = acc0, acc3 = acc0;
        // tiles 0,1
        #pragma unroll
        for (int p = 0; p < KS; ++p) {
            const unsigned short* ap = bs + abase + p * PC;
            acc0 = __builtin_amdgcn_mfma_f32_16x16x32_bf16(
                *reinterpret_cast<const bf16x8*>(ap +  0), bfrag[p], acc0, 0, 0, 0);
            acc1 = __builtin_amdgcn_mfma_f32_16x16x32_bf16(
                *reinterpret_cast<const bf16x8*>(ap + 16), bfrag[p], acc1, 0, 0, 0);
        }
        if (c + 1 < NCH) {                 // commit A (vmcnt waits), issue half B
            COMMIT_ITEM(tid,        nbs, s0);
            COMMIT_ITEM(tid + 512,  nbs, s1);
            COMMIT_ITEM(tid + 1024, nbs, s2);
            s0 = make_float4(0.f,0.f,0.f,0.f); s1 = s0; s2 = s0;
            ISSUE_ITEM(tid + 1536, gcb, s0);
            ISSUE_ITEM(tid + 2048, gcb, s1);
            if (tid + 2560 < NITEMS) ISSUE_ITEM(tid + 2560, gcb, s2);
        }
        // tiles 2,3
        #pragma unroll
        for (int p = 0; p < KS; ++p) {
            const unsigned short* ap = bs + abase + p * PC;
            acc2 = __builtin_amdgcn_mfma_f32_16x16x32_bf16(
                *reinterpret_cast<const bf16x8*>(ap + 32), bfrag[p], acc2, 0, 0, 0);
            acc3 = __builtin_amdgcn_mfma_f32_16x16x32_bf16(
                *reinterpret_cast<const bf16x8*>(ap + 48), bfrag[p], acc3, 0, 0, 0);
        }
        if (c + 1 < NCH) {                 // commit B, then release buffer swap
            COMMIT_ITEM(tid + 1536, nbs, s0);
            COMMIT_ITEM(tid + 2048, nbs, s1);
            if (tid + 2560 < NITEMS) COMMIT_ITEM(tid + 2560, nbs, s2);
            __syncthreads();
        }

        // stores of chunk c (overlap other waves' next compute)
        const int ocb   = c0 + c * CW;
        const int orow0 = r0 + wv * 16 + g * 4;
        #define STORE_TILE(t, a) {                                        \
            const int ocol = ocb + (t) * 16 + m;                          \
            if (ocol < N_OUT) {                                           \
                _Pragma("unroll")                                         \
                for (int r = 0; r < 4; ++r) {                             \
                    const int orow = orow0 + r;                           \
                    if (orow < N_OUT)                                     \
                        out[orow * N_OUT + ocol] = a[r] + b0;             \
                }                                                         \
            }                                                             \
        }
        STORE_TILE(0, acc0); STORE_TILE(1, acc1);
        STORE_TILE(2, acc2); STORE_TILE(3, acc3);
        #undef STORE_TILE
    }
}

extern "C" void kernel_launch(void* const* d_in, const int* in_sizes, int n_in,
                              void* d_out, int out_size, void* d_ws, size_t ws_size,
                              hipStream_t stream) {
    const float* x    = (const float*)d_in[0];
    const float* w    = (const float*)d_in[1];
    const float* bias = (const float*)d_in[2];
    float* out        = (float*)d_out;

    dim3 block(512);
    dim3 grid(16 * 32);   // 512 blocks, 1D, swizzled in-kernel; 2/CU, all resident
    Conv2DScratch_82025285419642_kernel<<<grid, block, 0, stream>>>(x, w, bias, out);
}

// Round 6
// 42.474 us; speedup vs baseline: 2.6738x; 1.4884x over previous
//
#include <hip/hip_runtime.h>

#define N_IN   4096
#define N_OUT  4082      // 4096 - 15 + 1
#define KS     15
#define TM     128       // output rows per block (8 chunks x 16)
#define TN     256       // output cols per block
#define CH     16        // output rows per chunk
#define NCH    8         // chunks per block
#define PR     142       // patch rows needed (TM + KS - 1)
#define PC     272       // patch cols staged (TN + 16)
#define C4R    68        // float4 chunks per patch row (PC/4)
#define RING   64        // ring rows (power of 2; window 30 + stage 16 = 46 <= 64)

// LDS: single 64-row ring, 64*272*2B = 34,816 B -> 2 blocks/CU at 512 thr.
// Bank note: pitch 272 bf16 = 136 words == 8 mod 32 -> row-to-row quad shift 2;
// 16-lane groups over 16 consecutive rows + g parity => 8 lanes/quad = b128 floor.
// Register note: bfrag 60 + acc 8 + staging <=20 + addr ~20 => ~110 < 128 cap.

typedef __attribute__((ext_vector_type(8))) short bf16x8;
typedef __attribute__((ext_vector_type(4))) float f32x4;

__device__ inline unsigned short f2bf(float f) {   // round-to-nearest-even
    unsigned u = __builtin_bit_cast(unsigned, f);
    u += 0x7FFFu + ((u >> 16) & 1u);
    return (unsigned short)(u >> 16);
}
__device__ inline ushort4 f2bf4(float4 v) {
    ushort4 b; b.x = f2bf(v.x); b.y = f2bf(v.y); b.z = f2bf(v.z); b.w = f2bf(v.w);
    return b;
}

// load one staging item (patch row = base + it/C4R) into v, zero-padded
#define ISSUE_ITEM(base, it, v) {                                         \
    const int _row = (base) + (it) / C4R;                                 \
    const int _c4  = (it) % C4R;                                          \
    const int _gr  = r0 + _row;                                           \
    const int _gc  = c0 + _c4 * 4;                                        \
    if (_row < PR && _gr < N_IN && _gc < N_IN)                            \
        v = *reinterpret_cast<const float4*>(&x[_gr * N_IN + _gc]);       \
}
// convert + write item into its ring slot
#define COMMIT_ITEM(base, it, v) {                                        \
    const int _row  = (base) + (it) / C4R;                                \
    const int _ring = _row & (RING - 1);                                  \
    const int _c4   = (it) % C4R;                                         \
    *reinterpret_cast<ushort4*>(&xs[_ring * PC + _c4 * 4]) = f2bf4(v);    \
}

__global__ __launch_bounds__(512, 4) void Conv2DScratch_82025285419642_kernel(
    const float* __restrict__ x, const float* __restrict__ w,
    const float* __restrict__ bias, float* __restrict__ out)
{
    __shared__ unsigned short xs[RING * PC];   // 34,816 B

    const int tid  = threadIdx.x;
    const int lane = tid & 63;
    const int wv   = tid >> 6;            // 0..7 : wave owns cols [32wv, 32wv+32)
    const int m    = lane & 15;           // A row within chunk band / D col
    const int g    = lane >> 4;           // k-group / D row group

    // bijective XCD-chunked block swizzle (512 blocks, 8 XCDs, 64 each)
    const int bid = blockIdx.x;
    const int s   = ((bid & 7) << 6) | (bid >> 3);
    const int c0  = (s & 15) * TN;        // output col base
    const int r0  = (s >> 4) * TM;        // output row base

    // ---- prologue: stage patch rows [0,32) ; build B frags while in flight ----
    float4 p0 = make_float4(0.f,0.f,0.f,0.f), p1 = p0, p2 = p0, p3 = p0, p4 = p0;
    ISSUE_ITEM(0, tid,        p0);
    ISSUE_ITEM(0, tid +  512, p1);
    ISSUE_ITEM(0, tid + 1024, p2);
    ISSUE_ITEM(0, tid + 1536, p3);
    if (tid < 128) ISSUE_ITEM(0, tid + 2048, p4);

    // B[(p,q)][n] = w[p][q-n]; lane: n = m, q = g*8+e  (verified in R2)
    bf16x8 bfrag[KS];
    #pragma unroll
    for (int p = 0; p < KS; ++p) {
        #pragma unroll
        for (int e = 0; e < 8; ++e) {
            const int idx = g * 8 + e - m;               // filter col
            const float vv = (idx >= 0 && idx < KS) ? w[p * KS + idx] : 0.f;
            bfrag[p][e] = (short)f2bf(vv);
        }
    }
    const float b0 = bias[0];

    COMMIT_ITEM(0, tid,        p0);
    COMMIT_ITEM(0, tid +  512, p1);
    COMMIT_ITEM(0, tid + 1024, p2);
    COMMIT_ITEM(0, tid + 1536, p3);
    if (tid < 128) COMMIT_ITEM(0, tid + 2048, p4);
    __syncthreads();

    const int colbase = wv * 32 + g * 8;   // A-frag col (bf16 elems) within ring row

    // ---- ring-pipelined chunk loop: compute rows [16c,16c+16), stage [32+16c,48+16c) ----
    for (int c = 0; c < NCH; ++c) {
        const int srow = 32 + c * CH;      // staging base row this chunk

        float4 s0 = make_float4(0.f,0.f,0.f,0.f), s1 = s0, s2 = s0;
        if (srow < PR) {                   // last chunk has nothing to stage
            ISSUE_ITEM(srow, tid,       s0);
            ISSUE_ITEM(srow, tid + 512, s1);
            if (tid < 64) ISSUE_ITEM(srow, tid + 1024, s2);
        }

        // compute 2 col-tiles of this chunk's 16-row band
        f32x4 acc0 = {0.f,0.f,0.f,0.f}, acc1 = acc0;
        const int prow0 = c * CH + m;      // patch row for p=0
        #pragma unroll
        for (int p = 0; p < KS; ++p) {
            const unsigned short* ap = &xs[((prow0 + p) & (RING - 1)) * PC + colbase];
            acc0 = __builtin_amdgcn_mfma_f32_16x16x32_bf16(
                *reinterpret_cast<const bf16x8*>(ap +  0), bfrag[p], acc0, 0, 0, 0);
            acc1 = __builtin_amdgcn_mfma_f32_16x16x32_bf16(
                *reinterpret_cast<const bf16x8*>(ap + 16), bfrag[p], acc1, 0, 0, 0);
        }

        if (srow < PR) {                   // commit staged rows (disjoint from reads)
            COMMIT_ITEM(srow, tid,       s0);
            COMMIT_ITEM(srow, tid + 512, s1);
            if (tid < 64) COMMIT_ITEM(srow, tid + 1024, s2);
        }

        // stores (before barrier; other waves may still compute chunk c — fine)
        const int orow0 = r0 + c * CH + g * 4;
        const int ocol0 = c0 + wv * 32 + m;
        #pragma unroll
        for (int r = 0; r < 4; ++r) {
            const int orow = orow0 + r;
            if (orow < N_OUT) {
                if (ocol0 < N_OUT)      out[orow * N_OUT + ocol0]      = acc0[r] + b0;
                if (ocol0 + 16 < N_OUT) out[orow * N_OUT + ocol0 + 16] = acc1[r] + b0;
            }
        }

        __syncthreads();                   // ring rows for chunk c+1 now visible
    }
}

extern "C" void kernel_launch(void* const* d_in, const int* in_sizes, int n_in,
                              void* d_out, int out_size, void* d_ws, size_t ws_size,
                              hipStream_t stream) {
    const float* x    = (const float*)d_in[0];
    const float* w    = (const float*)d_in[1];
    const float* bias = (const float*)d_in[2];
    float* out        = (float*)d_out;

    dim3 block(512);
    dim3 grid(16 * 32);   // 512 blocks, swizzled in-kernel; 2/CU, all resident
    Conv2DScratch_82025285419642_kernel<<<grid, block, 0, stream>>>(x, w, bias, out);
}